// Round 4
// baseline (917.633 us; speedup 1.0000x reference)
//
#include <hip/hip_runtime.h>
#include <math.h>

typedef unsigned short u16;
typedef unsigned int   u32;
typedef __attribute__((ext_vector_type(8))) short short8;
typedef __attribute__((ext_vector_type(4))) float f32x4;
typedef __attribute__((ext_vector_type(4))) u16   us4;

constexpr int Bc = 4, Sc = 1024, Hc = 1024, Nc = 16, Dc = 64, FFc = 4096;

// ---------------------------------------------------------------------------
// bf16 split helpers: v ~= hi + lo, each bf16 (RNE). ~16 mantissa bits total.
// ---------------------------------------------------------------------------
__device__ __forceinline__ u16 bfh(float v) {
  u32 u = __float_as_uint(v);
  return (u16)((u + 0x7FFFu + ((u >> 16) & 1u)) >> 16);
}
__device__ __forceinline__ void split2(float v, u16& h, u16& l) {
  h = bfh(v);
  l = bfh(v - __uint_as_float(((u32)h) << 16));
}

// async global->LDS, 16B per lane (dest = wave-uniform base + lane*16)
__device__ __forceinline__ void gl_lds16(const u16* g, u16* lds) {
  __builtin_amdgcn_global_load_lds(
      (const __attribute__((address_space(1))) void*)g,
      (__attribute__((address_space(3))) void*)lds, 16, 0, 0);
}

__device__ __forceinline__ f32x4 mfma_bf16(short8 a, short8 b, f32x4 c) {
  asm("v_mfma_f32_16x16x32_bf16 %0, %1, %2, %0" : "+v"(c) : "v"(a), "v"(b));
  return c;
}

// ---------------------------------------------------------------------------
// Conversion kernels
// ---------------------------------------------------------------------------
__global__ __launch_bounds__(256)
void split_copy(const float* __restrict__ in, u16* __restrict__ oh,
                u16* __restrict__ ol, int n4) {
  int i = blockIdx.x * 256 + threadIdx.x;
  if (i >= n4) return;
  f32x4 v = ((const f32x4*)in)[i];
  us4 h4, l4;
#pragma unroll
  for (int c = 0; c < 4; ++c) { u16 h, l; split2(v[c], h, l); h4[c] = h; l4[c] = l; }
  ((us4*)oh)[i] = h4;
  ((us4*)ol)[i] = l4;
}

// in[R][C] fp32 -> out_hi/lo[C][R] bf16 (transposed split)
__global__ __launch_bounds__(256)
void transpose_split(const float* __restrict__ in, u16* __restrict__ oh,
                     u16* __restrict__ ol, int R, int C) {
  __shared__ float t[32][33];
  const int c0 = blockIdx.x * 32, r0 = blockIdx.y * 32;
  const int tx = threadIdx.x & 31, ty = threadIdx.x >> 5;
#pragma unroll
  for (int j = 0; j < 4; ++j)
    t[ty + 8 * j][tx] = in[(size_t)(r0 + ty + 8 * j) * C + c0 + tx];
  __syncthreads();
#pragma unroll
  for (int j = 0; j < 4; ++j) {
    float v = t[tx][ty + 8 * j];
    u16 h, l; split2(v, h, l);
    size_t o = (size_t)(c0 + ty + 8 * j) * R + r0 + tx;
    oh[o] = h; ol[o] = l;
  }
}

// fused proj weight: Wt[5120][1024] bf16 hi/lo; cols per head n (320 each):
// [Wq_r | Wq_i | Wk_r | -Wk_i | Wv], each [H=1024 -> K][D=64]
__global__ __launch_bounds__(256)
void conv_wproj(const float* __restrict__ Wqr, const float* __restrict__ Wqi,
                const float* __restrict__ Wkr, const float* __restrict__ Wki,
                const float* __restrict__ Wv,  u16* __restrict__ oh,
                u16* __restrict__ ol) {
  __shared__ float t[32][33];
  const int c0 = blockIdx.x * 32, k0 = blockIdx.y * 32;
  const int n = c0 / 320, w0 = c0 - n * 320;
  const int chunk = w0 >> 6, d0 = w0 & 63;
  const float* src; float sgn = 1.f;
  switch (chunk) {
    case 0: src = Wqr; break;
    case 1: src = Wqi; break;
    case 2: src = Wkr; break;
    case 3: src = Wki; sgn = -1.f; break;
    default: src = Wv; break;
  }
  const int tx = threadIdx.x & 31, ty = threadIdx.x >> 5;
#pragma unroll
  for (int j = 0; j < 4; ++j)
    t[ty + 8 * j][tx] = sgn * src[((size_t)n * 1024 + k0 + ty + 8 * j) * 64 + d0 + tx];
  __syncthreads();
#pragma unroll
  for (int j = 0; j < 4; ++j) {
    float v = t[tx][ty + 8 * j];
    u16 h, l; split2(v, h, l);
    size_t o = (size_t)(c0 + ty + 8 * j) * 1024 + k0 + tx;
    oh[o] = h; ol[o] = l;
  }
}

// ---------------------------------------------------------------------------
// Split-bf16 MFMA GEMM, 128x128 tile, BK=32, 4 waves (2x2), 64x64 per wave.
// 2-PHASE double-buffered schedule (T3 minimum recipe): issue next-tile
// global_load_lds BEFORE current-tile ds_read+MFMA; ONE __syncthreads per
// K-step (drains vmcnt+lgkm). LDS 64KB -> 2 blocks/CU.
// MODE 0: proj epilogue -> qcat/kcat bf16 hi/lo + V^T bf16 hi/lo
// MODE 1: + bias + resid -> fp32 out
// MODE 2: + bias + relu  -> bf16 hi/lo out
// ---------------------------------------------------------------------------
struct GemmP {
  const u16 *Ah, *Al, *Bh, *Bl;
  int N, K;
  const float* bias;
  const float* resid;
  float* outf;
  u16 *oh, *ol;
  const float *bqr, *bqi, *bkr, *bki, *bv;
  const float *pqr, *pqi, *pkr, *pki;
  u16 *qh, *ql, *kh, *kl, *vth, *vtl;
};

template<int MODE>
__global__ __launch_bounds__(256)
void mfma_gemm(GemmP p) {
  __shared__ __attribute__((aligned(16))) u16 sA[2][2][128 * 32];  // [buf][plane]
  __shared__ __attribute__((aligned(16))) u16 sB[2][2][128 * 32];
  const int tid = threadIdx.x;
  const int w = tid >> 6, lane = tid & 63;
  const int wm = w >> 1, wn = w & 1;
  const int lrow = lane & 15, g = lane >> 4;
  const int bm = blockIdx.y * 128, bn = blockIdx.x * 128;
  const int K = p.K;

  // staging source (pre-swizzled involution, rule #21): 4 lanes/row-group
  const int srow = lane >> 2;
  const int sseg = (lane & 3) ^ ((lane >> 3) & 3);
  const int rowl0 = w * 32, rowl1 = w * 32 + 16;

  f32x4 acc[4][4];
#pragma unroll
  for (int i = 0; i < 4; ++i)
#pragma unroll
    for (int j = 0; j < 4; ++j) acc[i][j] = (f32x4){0.f, 0.f, 0.f, 0.f};

  auto stage = [&](int buf, int kb) {
    const size_t ga0 = (size_t)(bm + rowl0 + srow) * K + kb + sseg * 8;
    const size_t gb0 = (size_t)(bn + rowl0 + srow) * K + kb + sseg * 8;
    const size_t ga1 = (size_t)(bm + rowl1 + srow) * K + kb + sseg * 8;
    const size_t gb1 = (size_t)(bn + rowl1 + srow) * K + kb + sseg * 8;
    gl_lds16(p.Ah + ga0, &sA[buf][0][rowl0 * 32]);
    gl_lds16(p.Al + ga0, &sA[buf][1][rowl0 * 32]);
    gl_lds16(p.Bh + gb0, &sB[buf][0][rowl0 * 32]);
    gl_lds16(p.Bl + gb0, &sB[buf][1][rowl0 * 32]);
    gl_lds16(p.Ah + ga1, &sA[buf][0][rowl1 * 32]);
    gl_lds16(p.Al + ga1, &sA[buf][1][rowl1 * 32]);
    gl_lds16(p.Bh + gb1, &sB[buf][0][rowl1 * 32]);
    gl_lds16(p.Bl + gb1, &sB[buf][1][rowl1 * 32]);
  };

  const int sw = (lrow >> 1) & 3;
  auto compute = [&](int buf) {
    short8 ah[4], al[4], bh[4], bl[4];
#pragma unroll
    for (int mf = 0; mf < 4; ++mf) {
      int idx = (wm * 64 + mf * 16 + lrow) * 32 + ((g ^ sw) * 8);
      ah[mf] = *(const short8*)&sA[buf][0][idx];
      al[mf] = *(const short8*)&sA[buf][1][idx];
    }
#pragma unroll
    for (int nf = 0; nf < 4; ++nf) {
      int idx = (wn * 64 + nf * 16 + lrow) * 32 + ((g ^ sw) * 8);
      bh[nf] = *(const short8*)&sB[buf][0][idx];
      bl[nf] = *(const short8*)&sB[buf][1][idx];
    }
#pragma unroll
    for (int mf = 0; mf < 4; ++mf)
#pragma unroll
      for (int nf = 0; nf < 4; ++nf) {
        f32x4 a = acc[mf][nf];
        a = mfma_bf16(ah[mf], bh[nf], a);
        a = mfma_bf16(ah[mf], bl[nf], a);
        a = mfma_bf16(al[mf], bh[nf], a);
        acc[mf][nf] = a;
      }
  };

  // prologue
  stage(0, 0);
  __syncthreads();
  // main loop: K multiple of 64; 2 K-steps per iteration, static buf indices
  for (int kb = 0; kb < K; kb += 64) {
    stage(1, kb + 32);            // next tile in flight under compute
    compute(0);
    __syncthreads();              // drains vmcnt(0)+lgkmcnt(0), then barrier
    if (kb + 64 < K) stage(0, kb + 64);
    compute(1);
    __syncthreads();
  }

  // epilogue: C/D frag layout col = lane&15, row = (lane>>4)*4 + reg
#pragma unroll
  for (int nf = 0; nf < 4; ++nf) {
    const int c = bn + wn * 64 + nf * 16 + lrow;
    if (MODE == 0) {
      const int n = c / 320;
      const int wcol = c - n * 320;
      const int chunk = wcol >> 6, d = wcol & 63;
#pragma unroll
      for (int mf = 0; mf < 4; ++mf) {
        const int r0 = bm + wm * 64 + mf * 16 + g * 4;
        const int bb = r0 >> 10, s0 = r0 & 1023;
        const int head = bb * 16 + n;
        f32x4 a = acc[mf][nf];
        if (chunk == 4) {
          us4 hv, lv;
#pragma unroll
          for (int reg = 0; reg < 4; ++reg) {
            u16 hh, ll; split2(a[reg] + p.bv[n * 64 + d], hh, ll);
            hv[reg] = hh; lv[reg] = ll;
          }
          size_t o = ((size_t)head * 64 + d) * 1024 + s0;
          *(us4*)&p.vth[o] = hv;
          *(us4*)&p.vtl[o] = lv;
        } else {
#pragma unroll
          for (int reg = 0; reg < 4; ++reg) {
            const int s = s0 + reg;
            const size_t pidx = ((size_t)n * 1024 + s) * 64 + d;
            float val;
            u16 *dh, *dl;
            if (chunk == 0) {
              val = (a[reg] + p.bqr[n * 64 + d]) * 0.125f + p.pqr[pidx];
              dh = p.qh; dl = p.ql;
            } else if (chunk == 1) {
              val = (a[reg] + p.bqi[n * 64 + d]) * 0.125f + p.pqi[pidx];
              dh = p.qh; dl = p.ql;
            } else if (chunk == 2) {
              val = a[reg] + p.bkr[n * 64 + d] + p.pkr[pidx];
              dh = p.kh; dl = p.kl;
            } else {
              val = a[reg] - p.bki[n * 64 + d] - p.pki[pidx];
              dh = p.kh; dl = p.kl;
            }
            size_t o = ((size_t)head * 1024 + s) * 128 + (chunk & 1) * 64 + d;
            u16 hh, ll; split2(val, hh, ll);
            dh[o] = hh; dl[o] = ll;
          }
        }
      }
    } else {
      const float bb = p.bias[c];
#pragma unroll
      for (int mf = 0; mf < 4; ++mf) {
        const int r0 = bm + wm * 64 + mf * 16 + g * 4;
        f32x4 a = acc[mf][nf];
#pragma unroll
        for (int reg = 0; reg < 4; ++reg) {
          const int row = r0 + reg;
          const size_t o = (size_t)row * p.N + c;
          if (MODE == 1) {
            p.outf[o] = a[reg] + bb + p.resid[o];
          } else {
            float v = fmaxf(a[reg] + bb, 0.f);
            u16 h, l; split2(v, h, l);
            p.oh[o] = h; p.ol[o] = l;
          }
        }
      }
    }
  }
}

// ---------------------------------------------------------------------------
// MFMA flash attention (split-bf16). Block = (head, 64 q-rows), 4 waves x
// 16 rows each. KV tiles of 64. Q frags in registers; K [key][128] and
// V^T [d][key] in LDS with 16B-slot XOR swizzle (pre-swizzled global src,
// rule #21). P routed through per-wave swizzled LDS (slot ^= row>>1).
// scores C-layout: col=key=lane&15, row=(lane>>4)*4+reg -> row reductions
// are 16-lane shfl_xor.
// ---------------------------------------------------------------------------
__global__ __launch_bounds__(256)
void attn_mfma(const u16* __restrict__ qh, const u16* __restrict__ ql,
               const u16* __restrict__ kh, const u16* __restrict__ kl,
               const u16* __restrict__ vth, const u16* __restrict__ vtl,
               u16* __restrict__ ch, u16* __restrict__ cl) {
  __shared__ __attribute__((aligned(16))) u16 ksh[64 * 128];  // 16KB
  __shared__ __attribute__((aligned(16))) u16 ksl[64 * 128];  // 16KB
  __shared__ __attribute__((aligned(16))) u16 vsh[64 * 64];   // 8KB
  __shared__ __attribute__((aligned(16))) u16 vsl[64 * 64];   // 8KB
  __shared__ __attribute__((aligned(16))) u16 ps[4][2][16 * 64];  // 16KB

  const int tid = threadIdx.x;
  const int w = tid >> 6, lane = tid & 63;
  const int lo16 = lane & 15, hi4 = lane >> 4;
  const int n = blockIdx.y, b = blockIdx.z;
  const int head = b * Nc + n;
  const int q0 = blockIdx.x * 64;
  const u16* qbh = qh + (size_t)head * 1024 * 128;
  const u16* qbl = ql + (size_t)head * 1024 * 128;
  const u16* kbh = kh + (size_t)head * 1024 * 128;
  const u16* kbl = kl + (size_t)head * 1024 * 128;
  const u16* vbh = vth + (size_t)head * 64 * 1024;
  const u16* vbl = vtl + (size_t)head * 64 * 1024;

  // ---- stage Q (rows w*16..+15) into ks buffers, swizzled like K
  {
    const int ri = lane >> 4, slot = lane & 15;
#pragma unroll
    for (int i = 0; i < 4; ++i) {
      const int row = w * 16 + i * 4 + ri;
      const int sg = slot ^ (row & 7);
      const size_t src = (size_t)(q0 + row) * 128 + sg * 8;
      gl_lds16(qbh + src, &ksh[(w * 16 + i * 4) * 128]);
      gl_lds16(qbl + src, &ksl[(w * 16 + i * 4) * 128]);
    }
  }
  __syncthreads();
  // ---- read Q A-fragments into registers (row = lane&15 within wave tile)
  short8 qf[2][4];
  {
    const int qrow = w * 16 + lo16;
#pragma unroll
    for (int ks = 0; ks < 4; ++ks) {
      const int addr = qrow * 128 + (((ks * 4 + hi4) ^ (qrow & 7)) * 8);
      qf[0][ks] = *(const short8*)&ksh[addr];
      qf[1][ks] = *(const short8*)&ksl[addr];
    }
  }
  __syncthreads();  // drains lgkm: Q frags safe before K staging overwrites

  f32x4 acc_o[4];
  float m_[4], l_[4];
#pragma unroll
  for (int i = 0; i < 4; ++i) {
    acc_o[i] = (f32x4){0.f, 0.f, 0.f, 0.f};
    m_[i] = -1e30f; l_[i] = 0.f;
  }

  for (int kt = 0; kt < 16; ++kt) {
    const int k0 = kt * 64;
    // stage K rows w*16..+15 (both planes) and V^T d-rows w*16..+15
    {
      const int ri = lane >> 4, slot = lane & 15;
#pragma unroll
      for (int i = 0; i < 4; ++i) {
        const int row = w * 16 + i * 4 + ri;
        const int sg = slot ^ (row & 7);
        const size_t src = (size_t)(k0 + row) * 128 + sg * 8;
        gl_lds16(kbh + src, &ksh[(w * 16 + i * 4) * 128]);
        gl_lds16(kbl + src, &ksl[(w * 16 + i * 4) * 128]);
      }
      const int di = lane >> 3, vslot = lane & 7;
#pragma unroll
      for (int i = 0; i < 2; ++i) {
        const int d = w * 16 + i * 8 + di;
        const int sg = vslot ^ (d & 7);
        const size_t src = (size_t)d * 1024 + k0 + sg * 8;
        gl_lds16(vbh + src, &vsh[(w * 16 + i * 8) * 64]);
        gl_lds16(vbl + src, &vsl[(w * 16 + i * 8) * 64]);
      }
    }
    __syncthreads();

    // ---- QK^T: 16 rows x 64 keys per wave
    f32x4 sc[4];
#pragma unroll
    for (int cg = 0; cg < 4; ++cg) sc[cg] = (f32x4){0.f, 0.f, 0.f, 0.f};
#pragma unroll
    for (int cg = 0; cg < 4; ++cg) {
      const int key = cg * 16 + lo16;
#pragma unroll
      for (int ks = 0; ks < 4; ++ks) {
        const int addr = key * 128 + (((ks * 4 + hi4) ^ (key & 7)) * 8);
        short8 bhf = *(const short8*)&ksh[addr];
        short8 blf = *(const short8*)&ksl[addr];
        f32x4 a = sc[cg];
        a = mfma_bf16(qf[0][ks], bhf, a);
        a = mfma_bf16(qf[0][ks], blf, a);
        a = mfma_bf16(qf[1][ks], bhf, a);
        sc[cg] = a;
      }
    }
    // ---- online softmax (per row; 16-lane groups share a row)
    float pv[4][4];
#pragma unroll
    for (int reg = 0; reg < 4; ++reg) {
      float mx = fmaxf(fmaxf(sc[0][reg], sc[1][reg]),
                       fmaxf(sc[2][reg], sc[3][reg])) * 0.125f;
#pragma unroll
      for (int off = 1; off < 16; off <<= 1) mx = fmaxf(mx, __shfl_xor(mx, off));
      const float mn = fmaxf(m_[reg], mx);
      const float corr = __expf(m_[reg] - mn);
      m_[reg] = mn;
      float sum = 0.f;
#pragma unroll
      for (int cg = 0; cg < 4; ++cg) {
        float pe = __expf(sc[cg][reg] * 0.125f - mn);
        pv[cg][reg] = pe; sum += pe;
      }
#pragma unroll
      for (int off = 1; off < 16; off <<= 1) sum += __shfl_xor(sum, off);
      l_[reg] = l_[reg] * corr + sum;
#pragma unroll
      for (int cg = 0; cg < 4; ++cg) acc_o[cg][reg] *= corr;
    }
    // ---- write P (bf16 hi/lo) to per-wave LDS, slot ^= row>>1
#pragma unroll
    for (int cg = 0; cg < 4; ++cg) {
      const int key = cg * 16 + lo16;
#pragma unroll
      for (int reg = 0; reg < 4; ++reg) {
        const int row = hi4 * 4 + reg;
        const int pa = row * 64 + (((key >> 3) ^ (row >> 1)) * 8) + (key & 7);
        u16 hh, ll; split2(pv[cg][reg], hh, ll);
        ps[w][0][pa] = hh;
        ps[w][1][pa] = ll;
      }
    }
    // ---- PV: read P A-frags (row = lane&15), V^T B-frags
    short8 pah[2], pal[2];
#pragma unroll
    for (int ks2 = 0; ks2 < 2; ++ks2) {
      const int addr = lo16 * 64 + (((ks2 * 4 + hi4) ^ (lo16 >> 1)) * 8);
      pah[ks2] = *(const short8*)&ps[w][0][addr];
      pal[ks2] = *(const short8*)&ps[w][1][addr];
    }
#pragma unroll
    for (int cg = 0; cg < 4; ++cg) {
      const int d = cg * 16 + lo16;
#pragma unroll
      for (int ks2 = 0; ks2 < 2; ++ks2) {
        const int addr = d * 64 + (((ks2 * 4 + hi4) ^ (d & 7)) * 8);
        short8 vhf = *(const short8*)&vsh[addr];
        short8 vlf = *(const short8*)&vsl[addr];
        f32x4 a = acc_o[cg];
        a = mfma_bf16(pah[ks2], vhf, a);
        a = mfma_bf16(pah[ks2], vlf, a);
        a = mfma_bf16(pal[ks2], vhf, a);
        acc_o[cg] = a;
      }
    }
    __syncthreads();
  }

  // ---- epilogue: concat hi/lo bf16 [B*S][1024]
  float inv[4];
#pragma unroll
  for (int reg = 0; reg < 4; ++reg) inv[reg] = 1.f / l_[reg];
#pragma unroll
  for (int cg = 0; cg < 4; ++cg) {
#pragma unroll
    for (int reg = 0; reg < 4; ++reg) {
      const int qrow = q0 + w * 16 + hi4 * 4 + reg;
      const size_t o = ((size_t)b * Sc + qrow) * 1024 + n * 64 + cg * 16 + lo16;
      u16 hh, ll; split2(acc_o[cg][reg] * inv[reg], hh, ll);
      ch[o] = hh; cl[o] = ll;
    }
  }
}

// ---------------------------------------------------------------------------
// LayerNorm over last dim (1024); optional bf16 hi/lo split output.
// ---------------------------------------------------------------------------
template<bool SPLIT>
__global__ __launch_bounds__(256)
void ln_kernel(const float* __restrict__ in, const float* __restrict__ gam,
               const float* __restrict__ bet, float* __restrict__ out,
               u16* __restrict__ oh, u16* __restrict__ ol) {
  const int row = blockIdx.x, t = threadIdx.x;
  f32x4 v = ((const f32x4*)(in + (size_t)row * 1024))[t];
  float s = v[0] + v[1] + v[2] + v[3];
  float q = v[0] * v[0] + v[1] * v[1] + v[2] * v[2] + v[3] * v[3];
#pragma unroll
  for (int off = 1; off < 64; off <<= 1) {
    s += __shfl_xor(s, off);
    q += __shfl_xor(q, off);
  }
  __shared__ float red[8];
  int wv = t >> 6, lnid = t & 63;
  if (lnid == 0) { red[wv] = s; red[4 + wv] = q; }
  __syncthreads();
  s = red[0] + red[1] + red[2] + red[3];
  q = red[4] + red[5] + red[6] + red[7];
  float mu = s * (1.f / 1024.f);
  float var = q * (1.f / 1024.f) - mu * mu;
  float ri = rsqrtf(var + 1e-5f);
  f32x4 g4 = ((const f32x4*)gam)[t];
  f32x4 b4 = ((const f32x4*)bet)[t];
  f32x4 o;
#pragma unroll
  for (int c = 0; c < 4; ++c) o[c] = (v[c] - mu) * ri * g4[c] + b4[c];
  ((f32x4*)(out + (size_t)row * 1024))[t] = o;
  if (SPLIT) {
    us4 h4, l4;
#pragma unroll
    for (int c = 0; c < 4; ++c) {
      u16 hh, ll; split2(o[c], hh, ll);
      h4[c] = hh; l4[c] = ll;
    }
    *(us4*)&oh[(size_t)row * 1024 + t * 4] = h4;
    *(us4*)&ol[(size_t)row * 1024 + t * 4] = l4;
  }
}

// ---------------------------------------------------------------------------
extern "C" void kernel_launch(void* const* d_in, const int* in_sizes, int n_in,
                              void* d_out, int out_size, void* d_ws, size_t ws_size,
                              hipStream_t stream) {
  const float* x    = (const float*)d_in[0];
  const float* Wq_r = (const float*)d_in[1];
  const float* Wq_i = (const float*)d_in[2];
  const float* bq_r = (const float*)d_in[3];
  const float* bq_i = (const float*)d_in[4];
  const float* Wk_r = (const float*)d_in[5];
  const float* Wk_i = (const float*)d_in[6];
  const float* bk_r = (const float*)d_in[7];
  const float* bk_i = (const float*)d_in[8];
  const float* Wv   = (const float*)d_in[9];
  const float* bv   = (const float*)d_in[10];
  const float* pq_r = (const float*)d_in[11];
  const float* pq_i = (const float*)d_in[12];
  const float* pk_r = (const float*)d_in[13];
  const float* pk_i = (const float*)d_in[14];
  const float* Wo   = (const float*)d_in[15];
  const float* bo   = (const float*)d_in[16];
  const float* W1   = (const float*)d_in[17];
  const float* b1   = (const float*)d_in[18];
  const float* W2   = (const float*)d_in[19];
  const float* b2   = (const float*)d_in[20];
  const float* g1   = (const float*)d_in[21];
  const float* be1  = (const float*)d_in[22];
  const float* g2   = (const float*)d_in[23];
  const float* be2  = (const float*)d_in[24];

  char* Wb = (char*)d_ws;
  const size_t MB = (size_t)1 << 20;
  // lifetime-overlaid regions (152MB total):
  u16* qch = (u16*)(Wb + 0 * MB);     // 16MB -> hpre/hpre2 after attn
  u16* qcl = (u16*)(Wb + 16 * MB);    // 16MB -> ffh
  u16* kch = (u16*)(Wb + 32 * MB);    // 16MB -> ffh
  u16* kcl = (u16*)(Wb + 48 * MB);    // 16MB -> ffl
  u16* vth = (u16*)(Wb + 64 * MB);    // 8MB  -> ffl
  u16* vtl = (u16*)(Wb + 72 * MB);    // 8MB  -> ffl
  u16* xh  = (u16*)(Wb + 80 * MB);    // 8MB  -> concat_h -> w2h
  u16* xl  = (u16*)(Wb + 88 * MB);    // 8MB  -> concat_l -> w2l
  u16* ch  = xh; u16* cl = xl;
  u16* w2h = xh; u16* w2l = xl;
  u16* wph = (u16*)(Wb + 96 * MB);    // 10MB -> w1h after proj
  u16* wpl = (u16*)(Wb + 106 * MB);   // 10MB
  u16* w1h = (u16*)(Wb + 96 * MB);    // 8MB
  u16* w1l = (u16*)(Wb + 104 * MB);   // 8MB
  u16* woh = (u16*)(Wb + 116 * MB);   // 2MB
  u16* wol = (u16*)(Wb + 118 * MB);   // 2MB
  float* h1 = (float*)(Wb + 120 * MB);  // 16MB
  u16* h1h = (u16*)(Wb + 136 * MB);   // 8MB
  u16* h1l = (u16*)(Wb + 144 * MB);   // 8MB
  float* hpre = (float*)(Wb + 0 * MB);     // 16MB (over dead qch)
  u16* ffh = (u16*)(Wb + 16 * MB);    // 32MB (over dead qcl/kch)
  u16* ffl = (u16*)(Wb + 48 * MB);    // 32MB (over dead kcl/vt)

  // 1) input split
  split_copy<<<4096, 256, 0, stream>>>(x, xh, xl, (Bc * Sc * Hc) / 4);
  // 2) fused proj weights (transposed, ki negated)
  conv_wproj<<<dim3(160, 32), 256, 0, stream>>>(Wq_r, Wq_i, Wk_r, Wk_i, Wv, wph, wpl);
  // 3) proj GEMM [4096 x 5120 x 1024] -> qcat/kcat bf16 h/l + V^T h/l
  GemmP pp = {};
  pp.Ah = xh; pp.Al = xl; pp.Bh = wph; pp.Bl = wpl; pp.N = 5120; pp.K = 1024;
  pp.bqr = bq_r; pp.bqi = bq_i; pp.bkr = bk_r; pp.bki = bk_i; pp.bv = bv;
  pp.pqr = pq_r; pp.pqi = pq_i; pp.pkr = pk_r; pp.pki = pk_i;
  pp.qh = qch; pp.ql = qcl; pp.kh = kch; pp.kl = kcl; pp.vth = vth; pp.vtl = vtl;
  mfma_gemm<0><<<dim3(40, 32), 256, 0, stream>>>(pp);
  // 4) weight transposes (W1 reuses proj-weight region: must follow proj)
  transpose_split<<<dim3(128, 32), 256, 0, stream>>>(W1, w1h, w1l, 1024, 4096);
  transpose_split<<<dim3(32, 32), 256, 0, stream>>>(Wo, woh, wol, 1024, 1024);
  // 5) MFMA attention -> concat hi/lo (over dead xh/xl)
  attn_mfma<<<dim3(16, 16, 4), 256, 0, stream>>>(qch, qcl, kch, kcl, vth, vtl, ch, cl);
  // 6) out-proj + residual(x) -> hpre (over dead qch)
  GemmP po = {};
  po.Ah = ch; po.Al = cl; po.Bh = woh; po.Bl = wol; po.N = 1024; po.K = 1024;
  po.bias = bo; po.resid = x; po.outf = hpre;
  mfma_gemm<1><<<dim3(8, 32), 256, 0, stream>>>(po);
  // 7) W2 transpose (over dead concat, after out-proj consumed it)
  transpose_split<<<dim3(32, 128), 256, 0, stream>>>(W2, w2h, w2l, 4096, 1024);
  // 8) LN1 -> h1 fp32 + hi/lo
  ln_kernel<true><<<4096, 256, 0, stream>>>(hpre, g1, be1, h1, h1h, h1l);
  // 9) FF1 + ReLU -> ff hi/lo (over dead qcl/kc/vt)
  GemmP p1 = {};
  p1.Ah = h1h; p1.Al = h1l; p1.Bh = w1h; p1.Bl = w1l; p1.N = 4096; p1.K = 1024;
  p1.bias = b1; p1.oh = ffh; p1.ol = ffl;
  mfma_gemm<2><<<dim3(32, 32), 256, 0, stream>>>(p1);
  // 10) FF2 + residual(h1) -> hpre2
  GemmP p2 = {};
  p2.Ah = ffh; p2.Al = ffl; p2.Bh = w2h; p2.Bl = w2l; p2.N = 1024; p2.K = 4096;
  p2.bias = b2; p2.resid = h1; p2.outf = hpre;
  mfma_gemm<1><<<dim3(8, 32), 256, 0, stream>>>(p2);
  // 11) LN2 -> out
  ln_kernel<false><<<4096, 256, 0, stream>>>(hpre, g2, be2, (float*)d_out,
                                             nullptr, nullptr);
}

// Round 5
// 825.094 us; speedup vs baseline: 1.1122x; 1.1122x over previous
//
#include <hip/hip_runtime.h>
#include <math.h>

typedef unsigned short u16;
typedef unsigned int   u32;
typedef __attribute__((ext_vector_type(8))) short short8;
typedef __attribute__((ext_vector_type(4))) float f32x4;
typedef __attribute__((ext_vector_type(4))) u16   us4;

constexpr int Bc = 4, Sc = 1024, Hc = 1024, Nc = 16, Dc = 64, FFc = 4096;

// ---------------------------------------------------------------------------
// bf16 split helpers: v ~= hi + lo, each bf16 (RNE). ~16 mantissa bits total.
// ---------------------------------------------------------------------------
__device__ __forceinline__ u16 bfh(float v) {
  u32 u = __float_as_uint(v);
  return (u16)((u + 0x7FFFu + ((u >> 16) & 1u)) >> 16);
}
__device__ __forceinline__ void split2(float v, u16& h, u16& l) {
  h = bfh(v);
  l = bfh(v - __uint_as_float(((u32)h) << 16));
}

// async global->LDS, 16B per lane (dest = wave-uniform base + lane*16)
__device__ __forceinline__ void gl_lds16(const u16* g, u16* lds) {
  __builtin_amdgcn_global_load_lds(
      (const __attribute__((address_space(1))) void*)g,
      (__attribute__((address_space(3))) void*)lds, 16, 0, 0);
}

__device__ __forceinline__ f32x4 mfma_bf16(short8 a, short8 b, f32x4 c) {
  asm("v_mfma_f32_16x16x32_bf16 %0, %1, %2, %0" : "+v"(c) : "v"(a), "v"(b));
  return c;
}

// ---------------------------------------------------------------------------
// Conversion kernels
// ---------------------------------------------------------------------------
__global__ __launch_bounds__(256)
void split_copy(const float* __restrict__ in, u16* __restrict__ oh,
                u16* __restrict__ ol, int n4) {
  int i = blockIdx.x * 256 + threadIdx.x;
  if (i >= n4) return;
  f32x4 v = ((const f32x4*)in)[i];
  us4 h4, l4;
#pragma unroll
  for (int c = 0; c < 4; ++c) { u16 h, l; split2(v[c], h, l); h4[c] = h; l4[c] = l; }
  ((us4*)oh)[i] = h4;
  ((us4*)ol)[i] = l4;
}

// in[R][C] fp32 -> out_hi/lo[C][R] bf16 (transposed split)
__global__ __launch_bounds__(256)
void transpose_split(const float* __restrict__ in, u16* __restrict__ oh,
                     u16* __restrict__ ol, int R, int C) {
  __shared__ float t[32][33];
  const int c0 = blockIdx.x * 32, r0 = blockIdx.y * 32;
  const int tx = threadIdx.x & 31, ty = threadIdx.x >> 5;
#pragma unroll
  for (int j = 0; j < 4; ++j)
    t[ty + 8 * j][tx] = in[(size_t)(r0 + ty + 8 * j) * C + c0 + tx];
  __syncthreads();
#pragma unroll
  for (int j = 0; j < 4; ++j) {
    float v = t[tx][ty + 8 * j];
    u16 h, l; split2(v, h, l);
    size_t o = (size_t)(c0 + ty + 8 * j) * R + r0 + tx;
    oh[o] = h; ol[o] = l;
  }
}

// fused proj weight: Wt[5120][1024] bf16 hi/lo; cols per head n (320 each):
// [Wq_r | Wq_i | Wk_r | -Wk_i | Wv], each [H=1024 -> K][D=64]
__global__ __launch_bounds__(256)
void conv_wproj(const float* __restrict__ Wqr, const float* __restrict__ Wqi,
                const float* __restrict__ Wkr, const float* __restrict__ Wki,
                const float* __restrict__ Wv,  u16* __restrict__ oh,
                u16* __restrict__ ol) {
  __shared__ float t[32][33];
  const int c0 = blockIdx.x * 32, k0 = blockIdx.y * 32;
  const int n = c0 / 320, w0 = c0 - n * 320;
  const int chunk = w0 >> 6, d0 = w0 & 63;
  const float* src; float sgn = 1.f;
  switch (chunk) {
    case 0: src = Wqr; break;
    case 1: src = Wqi; break;
    case 2: src = Wkr; break;
    case 3: src = Wki; sgn = -1.f; break;
    default: src = Wv; break;
  }
  const int tx = threadIdx.x & 31, ty = threadIdx.x >> 5;
#pragma unroll
  for (int j = 0; j < 4; ++j)
    t[ty + 8 * j][tx] = sgn * src[((size_t)n * 1024 + k0 + ty + 8 * j) * 64 + d0 + tx];
  __syncthreads();
#pragma unroll
  for (int j = 0; j < 4; ++j) {
    float v = t[tx][ty + 8 * j];
    u16 h, l; split2(v, h, l);
    size_t o = (size_t)(c0 + ty + 8 * j) * 1024 + k0 + tx;
    oh[o] = h; ol[o] = l;
  }
}

// ---------------------------------------------------------------------------
// Split-bf16 MFMA GEMM, 128x128 tile, BK=32, 4 waves (2x2), 64x64 per wave.
// Single-buffer 2-barrier (r3-proven: dbuf cost occupancy > pipeline gain).
// XCD-aware bijective block swizzle (grids are multiples of 8).
// Split-K via blockIdx.z (slice length = p.K, row stride = p.lda).
// MODE 0: proj epilogue -> qcat/kcat bf16 hi/lo + V^T bf16 hi/lo
// MODE 1: pure partial -> fp32 out (outf / outf1 by z); bias+resid in ln_fuse
// MODE 2: + bias + relu  -> bf16 hi/lo out
// ---------------------------------------------------------------------------
struct GemmP {
  const u16 *Ah, *Al, *Bh, *Bl;
  int N, K, lda;
  const float* bias;
  float* outf;
  float* outf1;
  u16 *oh, *ol;
  const float *bqr, *bqi, *bkr, *bki, *bv;
  const float *pqr, *pqi, *pkr, *pki;
  u16 *qh, *ql, *kh, *kl, *vth, *vtl;
};

template<int MODE>
__global__ __launch_bounds__(256)
void mfma_gemm(GemmP p) {
  __shared__ __attribute__((aligned(16))) u16 sA[2][128 * 32];  // [plane]
  __shared__ __attribute__((aligned(16))) u16 sB[2][128 * 32];
  const int tid = threadIdx.x;
  const int w = tid >> 6, lane = tid & 63;
  const int wm = w >> 1, wn = w & 1;
  const int lrow = lane & 15, g = lane >> 4;
  // XCD-aware bijective swizzle (nwg % 8 == 0 for all our grids)
  const int gx = gridDim.x;
  const int id = blockIdx.y * gx + blockIdx.x;
  const int qq = (gx * gridDim.y) >> 3;
  const int sid = (id & 7) * qq + (id >> 3);
  const int bn = (sid % gx) * 128, bm = (sid / gx) * 128;
  const int K = p.K, lda = p.lda;
  const int koff = blockIdx.z * K;

  // staging source (pre-swizzled involution, rule #21)
  const int srow = lane >> 2;
  const int sseg = (lane & 3) ^ ((lane >> 3) & 3);
  const int rowl0 = w * 32, rowl1 = w * 32 + 16;

  f32x4 acc[4][4];
#pragma unroll
  for (int i = 0; i < 4; ++i)
#pragma unroll
    for (int j = 0; j < 4; ++j) acc[i][j] = (f32x4){0.f, 0.f, 0.f, 0.f};

  const int sw = (lrow >> 1) & 3;
  for (int kb = 0; kb < K; kb += 32) {
    const size_t ga0 = (size_t)(bm + rowl0 + srow) * lda + koff + kb + sseg * 8;
    const size_t gb0 = (size_t)(bn + rowl0 + srow) * lda + koff + kb + sseg * 8;
    const size_t ga1 = (size_t)(bm + rowl1 + srow) * lda + koff + kb + sseg * 8;
    const size_t gb1 = (size_t)(bn + rowl1 + srow) * lda + koff + kb + sseg * 8;
    gl_lds16(p.Ah + ga0, &sA[0][rowl0 * 32]);
    gl_lds16(p.Al + ga0, &sA[1][rowl0 * 32]);
    gl_lds16(p.Bh + gb0, &sB[0][rowl0 * 32]);
    gl_lds16(p.Bl + gb0, &sB[1][rowl0 * 32]);
    gl_lds16(p.Ah + ga1, &sA[0][rowl1 * 32]);
    gl_lds16(p.Al + ga1, &sA[1][rowl1 * 32]);
    gl_lds16(p.Bh + gb1, &sB[0][rowl1 * 32]);
    gl_lds16(p.Bl + gb1, &sB[1][rowl1 * 32]);
    __syncthreads();

    short8 ah[4], al[4], bh[4], bl[4];
#pragma unroll
    for (int mf = 0; mf < 4; ++mf) {
      int idx = (wm * 64 + mf * 16 + lrow) * 32 + ((g ^ sw) * 8);
      ah[mf] = *(const short8*)&sA[0][idx];
      al[mf] = *(const short8*)&sA[1][idx];
    }
#pragma unroll
    for (int nf = 0; nf < 4; ++nf) {
      int idx = (wn * 64 + nf * 16 + lrow) * 32 + ((g ^ sw) * 8);
      bh[nf] = *(const short8*)&sB[0][idx];
      bl[nf] = *(const short8*)&sB[1][idx];
    }
#pragma unroll
    for (int mf = 0; mf < 4; ++mf)
#pragma unroll
      for (int nf = 0; nf < 4; ++nf) {
        f32x4 a = acc[mf][nf];
        a = mfma_bf16(ah[mf], bh[nf], a);
        a = mfma_bf16(ah[mf], bl[nf], a);
        a = mfma_bf16(al[mf], bh[nf], a);
        acc[mf][nf] = a;
      }
    __syncthreads();
  }

  // epilogue: C/D frag layout col = lane&15, row = (lane>>4)*4 + reg
#pragma unroll
  for (int nf = 0; nf < 4; ++nf) {
    const int c = bn + wn * 64 + nf * 16 + lrow;
    if (MODE == 0) {
      const int n = c / 320;
      const int wcol = c - n * 320;
      const int chunk = wcol >> 6, d = wcol & 63;
#pragma unroll
      for (int mf = 0; mf < 4; ++mf) {
        const int r0 = bm + wm * 64 + mf * 16 + g * 4;
        const int bb = r0 >> 10, s0 = r0 & 1023;
        const int head = bb * 16 + n;
        f32x4 a = acc[mf][nf];
        if (chunk == 4) {
          us4 hv, lv;
#pragma unroll
          for (int reg = 0; reg < 4; ++reg) {
            u16 hh, ll; split2(a[reg] + p.bv[n * 64 + d], hh, ll);
            hv[reg] = hh; lv[reg] = ll;
          }
          size_t o = ((size_t)head * 64 + d) * 1024 + s0;
          *(us4*)&p.vth[o] = hv;
          *(us4*)&p.vtl[o] = lv;
        } else {
#pragma unroll
          for (int reg = 0; reg < 4; ++reg) {
            const int s = s0 + reg;
            const size_t pidx = ((size_t)n * 1024 + s) * 64 + d;
            float val;
            u16 *dh, *dl;
            if (chunk == 0) {
              val = (a[reg] + p.bqr[n * 64 + d]) * 0.125f + p.pqr[pidx];
              dh = p.qh; dl = p.ql;
            } else if (chunk == 1) {
              val = (a[reg] + p.bqi[n * 64 + d]) * 0.125f + p.pqi[pidx];
              dh = p.qh; dl = p.ql;
            } else if (chunk == 2) {
              val = a[reg] + p.bkr[n * 64 + d] + p.pkr[pidx];
              dh = p.kh; dl = p.kl;
            } else {
              val = a[reg] - p.bki[n * 64 + d] - p.pki[pidx];
              dh = p.kh; dl = p.kl;
            }
            size_t o = ((size_t)head * 1024 + s) * 128 + (chunk & 1) * 64 + d;
            u16 hh, ll; split2(val, hh, ll);
            dh[o] = hh; dl[o] = ll;
          }
        }
      }
    } else if (MODE == 1) {
      float* outp = blockIdx.z ? p.outf1 : p.outf;
#pragma unroll
      for (int mf = 0; mf < 4; ++mf) {
        const int r0 = bm + wm * 64 + mf * 16 + g * 4;
        f32x4 a = acc[mf][nf];
#pragma unroll
        for (int reg = 0; reg < 4; ++reg)
          outp[(size_t)(r0 + reg) * p.N + c] = a[reg];
      }
    } else {
      const float bb = p.bias[c];
#pragma unroll
      for (int mf = 0; mf < 4; ++mf) {
        const int r0 = bm + wm * 64 + mf * 16 + g * 4;
        f32x4 a = acc[mf][nf];
#pragma unroll
        for (int reg = 0; reg < 4; ++reg) {
          const size_t o = (size_t)(r0 + reg) * p.N + c;
          float v = fmaxf(a[reg] + bb, 0.f);
          u16 h, l; split2(v, h, l);
          p.oh[o] = h; p.ol[o] = l;
        }
      }
    }
  }
}

// ---------------------------------------------------------------------------
// MFMA flash attention (split-bf16). Block = (head, 64 q-rows), 4 waves x
// 16 rows each. KV tiles of 64. Q frags in registers; K [key][128] and
// V^T [d][key] in LDS with 16B-slot XOR swizzle (pre-swizzled global src,
// rule #21). P routed through per-wave swizzled LDS (slot ^= row>>1).
// ---------------------------------------------------------------------------
__global__ __launch_bounds__(256)
void attn_mfma(const u16* __restrict__ qh, const u16* __restrict__ ql,
               const u16* __restrict__ kh, const u16* __restrict__ kl,
               const u16* __restrict__ vth, const u16* __restrict__ vtl,
               u16* __restrict__ ch, u16* __restrict__ cl) {
  __shared__ __attribute__((aligned(16))) u16 ksh[64 * 128];  // 16KB
  __shared__ __attribute__((aligned(16))) u16 ksl[64 * 128];  // 16KB
  __shared__ __attribute__((aligned(16))) u16 vsh[64 * 64];   // 8KB
  __shared__ __attribute__((aligned(16))) u16 vsl[64 * 64];   // 8KB
  __shared__ __attribute__((aligned(16))) u16 ps[4][2][16 * 64];  // 16KB

  const int tid = threadIdx.x;
  const int w = tid >> 6, lane = tid & 63;
  const int lo16 = lane & 15, hi4 = lane >> 4;
  const int n = blockIdx.y, b = blockIdx.z;
  const int head = b * Nc + n;
  const int q0 = blockIdx.x * 64;
  const u16* qbh = qh + (size_t)head * 1024 * 128;
  const u16* qbl = ql + (size_t)head * 1024 * 128;
  const u16* kbh = kh + (size_t)head * 1024 * 128;
  const u16* kbl = kl + (size_t)head * 1024 * 128;
  const u16* vbh = vth + (size_t)head * 64 * 1024;
  const u16* vbl = vtl + (size_t)head * 64 * 1024;

  // ---- stage Q (rows w*16..+15) into ks buffers, swizzled like K
  {
    const int ri = lane >> 4, slot = lane & 15;
#pragma unroll
    for (int i = 0; i < 4; ++i) {
      const int row = w * 16 + i * 4 + ri;
      const int sg = slot ^ (row & 7);
      const size_t src = (size_t)(q0 + row) * 128 + sg * 8;
      gl_lds16(qbh + src, &ksh[(w * 16 + i * 4) * 128]);
      gl_lds16(qbl + src, &ksl[(w * 16 + i * 4) * 128]);
    }
  }
  __syncthreads();
  // ---- read Q A-fragments into registers (row = lane&15 within wave tile)
  short8 qf[2][4];
  {
    const int qrow = w * 16 + lo16;
#pragma unroll
    for (int ks = 0; ks < 4; ++ks) {
      const int addr = qrow * 128 + (((ks * 4 + hi4) ^ (qrow & 7)) * 8);
      qf[0][ks] = *(const short8*)&ksh[addr];
      qf[1][ks] = *(const short8*)&ksl[addr];
    }
  }
  __syncthreads();  // drains lgkm: Q frags safe before K staging overwrites

  f32x4 acc_o[4];
  float m_[4], l_[4];
#pragma unroll
  for (int i = 0; i < 4; ++i) {
    acc_o[i] = (f32x4){0.f, 0.f, 0.f, 0.f};
    m_[i] = -1e30f; l_[i] = 0.f;
  }

  for (int kt = 0; kt < 16; ++kt) {
    const int k0 = kt * 64;
    // stage K rows w*16..+15 (both planes) and V^T d-rows w*16..+15
    {
      const int ri = lane >> 4, slot = lane & 15;
#pragma unroll
      for (int i = 0; i < 4; ++i) {
        const int row = w * 16 + i * 4 + ri;
        const int sg = slot ^ (row & 7);
        const size_t src = (size_t)(k0 + row) * 128 + sg * 8;
        gl_lds16(kbh + src, &ksh[(w * 16 + i * 4) * 128]);
        gl_lds16(kbl + src, &ksl[(w * 16 + i * 4) * 128]);
      }
      const int di = lane >> 3, vslot = lane & 7;
#pragma unroll
      for (int i = 0; i < 2; ++i) {
        const int d = w * 16 + i * 8 + di;
        const int sg = vslot ^ (d & 7);
        const size_t src = (size_t)d * 1024 + k0 + sg * 8;
        gl_lds16(vbh + src, &vsh[(w * 16 + i * 8) * 64]);
        gl_lds16(vbl + src, &vsl[(w * 16 + i * 8) * 64]);
      }
    }
    __syncthreads();

    // ---- QK^T: 16 rows x 64 keys per wave
    f32x4 sc[4];
#pragma unroll
    for (int cg = 0; cg < 4; ++cg) sc[cg] = (f32x4){0.f, 0.f, 0.f, 0.f};
#pragma unroll
    for (int cg = 0; cg < 4; ++cg) {
      const int key = cg * 16 + lo16;
#pragma unroll
      for (int ks = 0; ks < 4; ++ks) {
        const int addr = key * 128 + (((ks * 4 + hi4) ^ (key & 7)) * 8);
        short8 bhf = *(const short8*)&ksh[addr];
        short8 blf = *(const short8*)&ksl[addr];
        f32x4 a = sc[cg];
        a = mfma_bf16(qf[0][ks], bhf, a);
        a = mfma_bf16(qf[0][ks], blf, a);
        a = mfma_bf16(qf[1][ks], bhf, a);
        sc[cg] = a;
      }
    }
    // ---- online softmax (per row; 16-lane groups share a row)
    float pv[4][4];
#pragma unroll
    for (int reg = 0; reg < 4; ++reg) {
      float mx = fmaxf(fmaxf(sc[0][reg], sc[1][reg]),
                       fmaxf(sc[2][reg], sc[3][reg])) * 0.125f;
#pragma unroll
      for (int off = 1; off < 16; off <<= 1) mx = fmaxf(mx, __shfl_xor(mx, off));
      const float mn = fmaxf(m_[reg], mx);
      const float corr = __expf(m_[reg] - mn);
      m_[reg] = mn;
      float sum = 0.f;
#pragma unroll
      for (int cg = 0; cg < 4; ++cg) {
        float pe = __expf(sc[cg][reg] * 0.125f - mn);
        pv[cg][reg] = pe; sum += pe;
      }
#pragma unroll
      for (int off = 1; off < 16; off <<= 1) sum += __shfl_xor(sum, off);
      l_[reg] = l_[reg] * corr + sum;
#pragma unroll
      for (int cg = 0; cg < 4; ++cg) acc_o[cg][reg] *= corr;
    }
    // ---- write P (bf16 hi/lo) to per-wave LDS, slot ^= row>>1
#pragma unroll
    for (int cg = 0; cg < 4; ++cg) {
      const int key = cg * 16 + lo16;
#pragma unroll
      for (int reg = 0; reg < 4; ++reg) {
        const int row = hi4 * 4 + reg;
        const int pa = row * 64 + (((key >> 3) ^ (row >> 1)) * 8) + (key & 7);
        u16 hh, ll; split2(pv[cg][reg], hh, ll);
        ps[w][0][pa] = hh;
        ps[w][1][pa] = ll;
      }
    }
    // ---- PV: read P A-frags (row = lane&15), V^T B-frags
    short8 pah[2], pal[2];
#pragma unroll
    for (int ks2 = 0; ks2 < 2; ++ks2) {
      const int addr = lo16 * 64 + (((ks2 * 4 + hi4) ^ (lo16 >> 1)) * 8);
      pah[ks2] = *(const short8*)&ps[w][0][addr];
      pal[ks2] = *(const short8*)&ps[w][1][addr];
    }
#pragma unroll
    for (int cg = 0; cg < 4; ++cg) {
      const int d = cg * 16 + lo16;
#pragma unroll
      for (int ks2 = 0; ks2 < 2; ++ks2) {
        const int addr = d * 64 + (((ks2 * 4 + hi4) ^ (d & 7)) * 8);
        short8 vhf = *(const short8*)&vsh[addr];
        short8 vlf = *(const short8*)&vsl[addr];
        f32x4 a = acc_o[cg];
        a = mfma_bf16(pah[ks2], vhf, a);
        a = mfma_bf16(pah[ks2], vlf, a);
        a = mfma_bf16(pal[ks2], vhf, a);
        acc_o[cg] = a;
      }
    }
    __syncthreads();
  }

  // ---- epilogue: concat hi/lo bf16 [B*S][1024]
  float inv[4];
#pragma unroll
  for (int reg = 0; reg < 4; ++reg) inv[reg] = 1.f / l_[reg];
#pragma unroll
  for (int cg = 0; cg < 4; ++cg) {
#pragma unroll
    for (int reg = 0; reg < 4; ++reg) {
      const int qrow = q0 + w * 16 + hi4 * 4 + reg;
      const size_t o = ((size_t)b * Sc + qrow) * 1024 + n * 64 + cg * 16 + lo16;
      u16 hh, ll; split2(acc_o[cg][reg] * inv[reg], hh, ll);
      ch[o] = hh; cl[o] = ll;
    }
  }
}

// ---------------------------------------------------------------------------
// Fused LayerNorm: v = P0 + P1 + resid + bias(col), then LN(v)*g+beta.
// Always writes fp32 out; SPLIT also writes bf16 hi/lo.
// ---------------------------------------------------------------------------
template<bool SPLIT>
__global__ __launch_bounds__(256)
void ln_fuse(const float* __restrict__ P0, const float* __restrict__ P1,
             const float* __restrict__ resid, const float* __restrict__ bias,
             const float* __restrict__ gam, const float* __restrict__ bet,
             float* __restrict__ out, u16* __restrict__ oh,
             u16* __restrict__ ol) {
  const int row = blockIdx.x, t = threadIdx.x;
  const size_t base = (size_t)row * 1024;
  f32x4 v = ((const f32x4*)(P0 + base))[t];
  f32x4 p1 = ((const f32x4*)(P1 + base))[t];
  f32x4 rr = ((const f32x4*)(resid + base))[t];
  f32x4 bb = ((const f32x4*)bias)[t];
#pragma unroll
  for (int c = 0; c < 4; ++c) v[c] += p1[c] + rr[c] + bb[c];
  float s = v[0] + v[1] + v[2] + v[3];
  float q = v[0] * v[0] + v[1] * v[1] + v[2] * v[2] + v[3] * v[3];
#pragma unroll
  for (int off = 1; off < 64; off <<= 1) {
    s += __shfl_xor(s, off);
    q += __shfl_xor(q, off);
  }
  __shared__ float red[8];
  int wv = t >> 6, lnid = t & 63;
  if (lnid == 0) { red[wv] = s; red[4 + wv] = q; }
  __syncthreads();
  s = red[0] + red[1] + red[2] + red[3];
  q = red[4] + red[5] + red[6] + red[7];
  float mu = s * (1.f / 1024.f);
  float var = q * (1.f / 1024.f) - mu * mu;
  float ri = rsqrtf(var + 1e-5f);
  f32x4 g4 = ((const f32x4*)gam)[t];
  f32x4 b4 = ((const f32x4*)bet)[t];
  f32x4 o;
#pragma unroll
  for (int c = 0; c < 4; ++c) o[c] = (v[c] - mu) * ri * g4[c] + b4[c];
  ((f32x4*)(out + base))[t] = o;
  if (SPLIT) {
    us4 h4, l4;
#pragma unroll
    for (int c = 0; c < 4; ++c) {
      u16 hh, ll; split2(o[c], hh, ll);
      h4[c] = hh; l4[c] = ll;
    }
    *(us4*)&oh[base + t * 4] = h4;
    *(us4*)&ol[base + t * 4] = l4;
  }
}

// ---------------------------------------------------------------------------
extern "C" void kernel_launch(void* const* d_in, const int* in_sizes, int n_in,
                              void* d_out, int out_size, void* d_ws, size_t ws_size,
                              hipStream_t stream) {
  const float* x    = (const float*)d_in[0];
  const float* Wq_r = (const float*)d_in[1];
  const float* Wq_i = (const float*)d_in[2];
  const float* bq_r = (const float*)d_in[3];
  const float* bq_i = (const float*)d_in[4];
  const float* Wk_r = (const float*)d_in[5];
  const float* Wk_i = (const float*)d_in[6];
  const float* bk_r = (const float*)d_in[7];
  const float* bk_i = (const float*)d_in[8];
  const float* Wv   = (const float*)d_in[9];
  const float* bv   = (const float*)d_in[10];
  const float* pq_r = (const float*)d_in[11];
  const float* pq_i = (const float*)d_in[12];
  const float* pk_r = (const float*)d_in[13];
  const float* pk_i = (const float*)d_in[14];
  const float* Wo   = (const float*)d_in[15];
  const float* bo   = (const float*)d_in[16];
  const float* W1   = (const float*)d_in[17];
  const float* b1   = (const float*)d_in[18];
  const float* W2   = (const float*)d_in[19];
  const float* b2   = (const float*)d_in[20];
  const float* g1   = (const float*)d_in[21];
  const float* be1  = (const float*)d_in[22];
  const float* g2   = (const float*)d_in[23];
  const float* be2  = (const float*)d_in[24];

  char* Wb = (char*)d_ws;
  const size_t MB = (size_t)1 << 20;
  // lifetime-overlaid regions (152MB total):
  u16* qch = (u16*)(Wb + 0 * MB);      // 16MB -> P0 -> ffh(0-32)
  u16* qcl = (u16*)(Wb + 16 * MB);     // 16MB -> P1
  u16* kch = (u16*)(Wb + 32 * MB);     // 16MB -> ffl(32-64)
  u16* kcl = (u16*)(Wb + 48 * MB);     // 16MB
  u16* vth = (u16*)(Wb + 64 * MB);     // 8MB  -> Q0(64-80)
  u16* vtl = (u16*)(Wb + 72 * MB);     // 8MB
  u16* xh  = (u16*)(Wb + 80 * MB);     // 8MB  -> concat_h -> w2h
  u16* xl  = (u16*)(Wb + 88 * MB);     // 8MB  -> concat_l -> w2l
  u16* ch  = xh; u16* cl = xl;
  u16* w2h = xh; u16* w2l = xl;
  u16* wph = (u16*)(Wb + 96 * MB);     // 10MB -> w1h/w1l/wo after proj
  u16* wpl = (u16*)(Wb + 106 * MB);    // 10MB
  u16* w1h = (u16*)(Wb + 96 * MB);     // 8MB  -> Q1(96-112) after FF1
  u16* w1l = (u16*)(Wb + 104 * MB);    // 8MB
  u16* woh = (u16*)(Wb + 112 * MB);    // 2MB
  u16* wol = (u16*)(Wb + 114 * MB);    // 2MB
  float* h1 = (float*)(Wb + 120 * MB); // 16MB (live until LN2)
  u16* h1h = (u16*)(Wb + 136 * MB);    // 8MB
  u16* h1l = (u16*)(Wb + 144 * MB);    // 8MB
  float* P0 = (float*)(Wb + 0 * MB);   // out-proj partials (qch/qcl dead)
  float* P1 = (float*)(Wb + 16 * MB);
  u16* ffh = (u16*)(Wb + 0 * MB);      // 32MB (P0/P1 dead after LN1)
  u16* ffl = (u16*)(Wb + 32 * MB);     // 32MB (kch/kcl dead after attn)
  float* Q0 = (float*)(Wb + 64 * MB);  // FF2 partials (vt dead)
  float* Q1 = (float*)(Wb + 96 * MB);  // (w1 dead after FF1)

  // 1) input split
  split_copy<<<4096, 256, 0, stream>>>(x, xh, xl, (Bc * Sc * Hc) / 4);
  // 2) fused proj weights (transposed, ki negated)
  conv_wproj<<<dim3(160, 32), 256, 0, stream>>>(Wq_r, Wq_i, Wk_r, Wk_i, Wv, wph, wpl);
  // 3) proj GEMM [4096 x 5120 x 1024] -> qcat/kcat bf16 h/l + V^T h/l
  GemmP pp = {};
  pp.Ah = xh; pp.Al = xl; pp.Bh = wph; pp.Bl = wpl;
  pp.N = 5120; pp.K = 1024; pp.lda = 1024;
  pp.bqr = bq_r; pp.bqi = bq_i; pp.bkr = bk_r; pp.bki = bk_i; pp.bv = bv;
  pp.pqr = pq_r; pp.pqi = pq_i; pp.pkr = pk_r; pp.pki = pk_i;
  pp.qh = qch; pp.ql = qcl; pp.kh = kch; pp.kl = kcl; pp.vth = vth; pp.vtl = vtl;
  mfma_gemm<0><<<dim3(40, 32), 256, 0, stream>>>(pp);
  // 4) weight transposes (reuse proj-weight region: must follow proj)
  transpose_split<<<dim3(128, 32), 256, 0, stream>>>(W1, w1h, w1l, 1024, 4096);
  transpose_split<<<dim3(32, 32), 256, 0, stream>>>(Wo, woh, wol, 1024, 1024);
  // 5) MFMA attention -> concat hi/lo (over dead xh/xl)
  attn_mfma<<<dim3(16, 16, 4), 256, 0, stream>>>(qch, qcl, kch, kcl, vth, vtl, ch, cl);
  // 6) out-proj, split-K=2 -> partials P0/P1 (over dead qch/qcl)
  GemmP po = {};
  po.Ah = ch; po.Al = cl; po.Bh = woh; po.Bl = wol;
  po.N = 1024; po.K = 512; po.lda = 1024;
  po.outf = P0; po.outf1 = P1;
  mfma_gemm<1><<<dim3(8, 32, 2), 256, 0, stream>>>(po);
  // 7) W2 transpose (over dead concat, after out-proj consumed it)
  transpose_split<<<dim3(32, 128), 256, 0, stream>>>(W2, w2h, w2l, 4096, 1024);
  // 8) LN1 = LN(P0+P1+x+bo) -> h1 fp32 + hi/lo
  ln_fuse<true><<<4096, 256, 0, stream>>>(P0, P1, x, bo, g1, be1, h1, h1h, h1l);
  // 9) FF1 + ReLU -> ff hi/lo (over dead P0/P1 and kch/kcl)
  GemmP p1 = {};
  p1.Ah = h1h; p1.Al = h1l; p1.Bh = w1h; p1.Bl = w1l;
  p1.N = 4096; p1.K = 1024; p1.lda = 1024;
  p1.bias = b1; p1.oh = ffh; p1.ol = ffl;
  mfma_gemm<2><<<dim3(32, 32), 256, 0, stream>>>(p1);
  // 10) FF2, split-K=2 -> partials Q0/Q1 (over dead vt and w1)
  GemmP p2 = {};
  p2.Ah = ffh; p2.Al = ffl; p2.Bh = w2h; p2.Bl = w2l;
  p2.N = 1024; p2.K = 2048; p2.lda = 4096;
  p2.outf = Q0; p2.outf1 = Q1;
  mfma_gemm<1><<<dim3(8, 32, 2), 256, 0, stream>>>(p2);
  // 11) LN2 = LN(Q0+Q1+h1+b2) -> out
  ln_fuse<false><<<4096, 256, 0, stream>>>(Q0, Q1, h1, b2, g2, be2,
                                           (float*)d_out, nullptr, nullptr);
}